// Round 2
// baseline (683.078 us; speedup 1.0000x reference)
//
#include <hip/hip_runtime.h>

// Problem constants
#define S_  2048
#define D_  1024
#define H_  16
#define B_  4

typedef __attribute__((ext_vector_type(8))) short short8;
typedef __attribute__((ext_vector_type(4))) float f32x4;
typedef __attribute__((ext_vector_type(2))) _Float16 half2v;

__device__ __forceinline__ unsigned short f2bf(float f) {
  unsigned int u = __float_as_uint(f);
  u += 0x7fffu + ((u >> 16) & 1u);      // round-to-nearest-even
  return (unsigned short)(u >> 16);
}
__device__ __forceinline__ unsigned int pack2(float a, float b) {
  return (unsigned int)f2bf(a) | ((unsigned int)f2bf(b) << 16);
}

// 0.125 (1/sqrt(DK)) * log2(e): use exp2 (native v_exp_f32)
#define SCL   0.18033688011112042f
#define EBIAS 12.0f   // uniform per-problem bias: cancels in normalization

// ---------------------------------------------------------------------------
// Single-pass fused attention.
// Block = 256 threads (4 waves), one 16-row q-tile, full S.
// Per 128-key chunk: stage K (bf16, XOR-swizzled LDS), each wave computes its
// 2 kt tiles via MFMA, e' = exp2(s*SCL-EBIAS) kept in VGPRs as packed fp16
// (static indices: c0 loop fully unrolled). After row-sum reduce, a register-
// resident write phase streams normalized attn (nontemporal) and accumulates
// deterministic fixed-point column sums via u64 atomics.
// grid = B*H * (S/16) = 8192 blocks, XCD-swizzled so all 128 q-tiles of one
// (b,h) run consecutively on one XCD (K-slice stays L2-resident).
// ---------------------------------------------------------------------------
__global__ __launch_bounds__(256, 3) void attn_fused(
    const float* __restrict__ x, const int* __restrict__ sl32,
    float* __restrict__ attn, unsigned long long* __restrict__ c64)
{
  __shared__ __align__(16) unsigned short kbuf[128 * 64]; // 16 KB staged keys
  __shared__ __align__(16) float wbuf[4][16];
  __shared__ float invbuf[16];

  const int n    = blockIdx.x;
  const int xcd  = n & 7;
  const int slot = n >> 3;                 // 0..1023 per XCD
  const int bh   = (slot >> 7) * 8 + xcd;  // 0..63
  const int qt   = slot & 127;             // 0..127 q-tiles of 16 rows
  const int b    = bh >> 4;
  const int h    = bh & 15;
  const int tid  = threadIdx.x;
  const int wv   = tid >> 6;               // wave 0..3 -> kt in {wv, wv+4}
  const int lane = tid & 63;
  const int lo   = lane & 15;
  const int g    = lane >> 4;

  // seq_lens dtype auto-detect (values >= 1024 -> int64 layout has word1==0)
  const bool is64 = (sl32[1] == 0);
  const int seqlen = is64 ? sl32[2 * b] : sl32[b];

  // Q fragment (A-frag): row = lo, k = g*8 + i + 32*s
  short8 aq[2];
  {
    const float* qp = x + ((size_t)b * S_ + qt * 16 + lo) * D_ + h * 64 + g * 8;
#pragma unroll
    for (int s = 0; s < 2; ++s) {
      const float4* p = (const float4*)(qp + s * 32);
      float4 v0 = p[0], v1 = p[1];
      short8 t;
      t[0] = (short)f2bf(v0.x); t[1] = (short)f2bf(v0.y);
      t[2] = (short)f2bf(v0.z); t[3] = (short)f2bf(v0.w);
      t[4] = (short)f2bf(v1.x); t[5] = (short)f2bf(v1.y);
      t[6] = (short)f2bf(v1.z); t[7] = (short)f2bf(v1.w);
      aq[s] = t;
    }
  }

  const int sr = tid >> 1, sh = tid & 1;   // staging: key row, 32-dim half
  auto stage = [&](int c0) {
    const float* kp = x + ((size_t)b * S_ + (c0 * 128 + sr)) * D_ + h * 64 + sh * 32;
#pragma unroll
    for (int q = 0; q < 4; ++q) {
      float4 v0 = ((const float4*)kp)[2 * q];
      float4 v1 = ((const float4*)kp)[2 * q + 1];
      uint4 w;
      w.x = pack2(v0.x, v0.y);
      w.y = pack2(v0.z, v0.w);
      w.z = pack2(v1.x, v1.y);
      w.w = pack2(v1.z, v1.w);
      const int cs = (sh * 4 + q) ^ (sr & 7);
      *(uint4*)&kbuf[sr * 64 + cs * 8] = w;
    }
  };

  auto qk_tile = [&](int kt) -> f32x4 {
    const int key = kt * 16 + lo;  // B-frag col
    f32x4 acc = {0.f, 0.f, 0.f, 0.f};
#pragma unroll
    for (int s = 0; s < 2; ++s) {
      const int cs = (s * 4 + g) ^ (key & 7);
      short8 bq = *(const short8*)&kbuf[key * 64 + cs * 8];
      acc = __builtin_amdgcn_mfma_f32_16x16x32_bf16(aq[s], bq, acc, 0, 0, 0);
    }
    return acc;
  };

  // ---------------- Single QK^T pass: e' into registers ----------------
  unsigned int ev[64];                     // packed fp16, statically indexed
  float rsum[4] = {0.f, 0.f, 0.f, 0.f};
#pragma unroll
  for (int c0 = 0; c0 < 16; ++c0) {
    __syncthreads();
    stage(c0);
    __syncthreads();
#pragma unroll
    for (int i = 0; i < 2; ++i) {
      const int kt = wv + 4 * i;
      f32x4 acc = qk_tile(kt);
      const int kg = c0 * 128 + kt * 16 + lo;
      const bool valid = kg < seqlen;
      float e0 = valid ? exp2f(acc[0] * SCL - EBIAS) : 0.f;
      float e1 = valid ? exp2f(acc[1] * SCL - EBIAS) : 0.f;
      float e2 = valid ? exp2f(acc[2] * SCL - EBIAS) : 0.f;
      float e3 = valid ? exp2f(acc[3] * SCL - EBIAS) : 0.f;
      rsum[0] += e0; rsum[1] += e1; rsum[2] += e2; rsum[3] += e3;
      ev[(c0 * 2 + i) * 2 + 0] =
          __builtin_bit_cast(unsigned int, __builtin_amdgcn_cvt_pkrtz(e0, e1));
      ev[(c0 * 2 + i) * 2 + 1] =
          __builtin_bit_cast(unsigned int, __builtin_amdgcn_cvt_pkrtz(e2, e3));
    }
  }

  // ---------------- Row-sum reduction -> 1/l ----------------
#pragma unroll
  for (int r = 0; r < 4; ++r) {
    float v = rsum[r];
    v += __shfl_xor(v, 1);
    v += __shfl_xor(v, 2);
    v += __shfl_xor(v, 4);
    v += __shfl_xor(v, 8);
    rsum[r] = v;                      // all 16 col-lanes now hold wave partial
  }
  if (lo == 0) {
    float4 wq = make_float4(rsum[0], rsum[1], rsum[2], rsum[3]);
    *(float4*)&wbuf[wv][g * 4] = wq;
  }
  __syncthreads();
  if (tid < 16)
    invbuf[tid] = 1.0f / (wbuf[0][tid] + wbuf[1][tid] + wbuf[2][tid] + wbuf[3][tid]);
  __syncthreads();

  float vinv[4];
#pragma unroll
  for (int r = 0; r < 4; ++r) vinv[r] = invbuf[g * 4 + r];

  // ---------------- Write phase: normalize, store, column sums -------------
  float* pr = attn + (size_t)bh * S_ * S_ + ((size_t)qt * 16 + g * 4) * S_ + lo;
  unsigned long long* cb = c64 + bh * 2048;
#pragma unroll
  for (int c0 = 0; c0 < 16; ++c0) {
#pragma unroll
    for (int i = 0; i < 2; ++i) {
      const int kt = wv + 4 * i;
      const int off = c0 * 128 + kt * 16;
      half2v h0 = __builtin_bit_cast(half2v, ev[(c0 * 2 + i) * 2 + 0]);
      half2v h1 = __builtin_bit_cast(half2v, ev[(c0 * 2 + i) * 2 + 1]);
      float a0 = (float)h0[0] * vinv[0];
      float a1 = (float)h0[1] * vinv[1];
      float a2 = (float)h1[0] * vinv[2];
      float a3 = (float)h1[1] * vinv[3];
      __builtin_nontemporal_store(a0, pr + off);
      __builtin_nontemporal_store(a1, pr + (size_t)1 * S_ + off);
      __builtin_nontemporal_store(a2, pr + (size_t)2 * S_ + off);
      __builtin_nontemporal_store(a3, pr + (size_t)3 * S_ + off);
      float cv = a0 + a1 + a2 + a3;
      cv += __shfl_xor(cv, 16);
      cv += __shfl_xor(cv, 32);       // 16-row column sum, all lanes
      if (lane < 16) {
        unsigned int q32 = __float2uint_rn(cv * 16777216.0f);
        atomicAdd(&cb[off + lane], (unsigned long long)q32);
      }
    }
  }
}

// csum[b][h*64+d] = sum_k c[bh][k] * x[b][k][h*64+d]
__global__ __launch_bounds__(256) void csum_k(const unsigned long long* __restrict__ c64,
                                              const float* __restrict__ x,
                                              float* __restrict__ csum) {
  __shared__ float part[4][64];
  const int bh = blockIdx.x, b = bh >> 4, h = bh & 15;
  const int seg = threadIdx.x >> 6, d = threadIdx.x & 63;
  const unsigned long long* cb = c64 + bh * 2048;
  const float* xb = x + (size_t)b * S_ * D_ + h * 64 + d;
  float acc = 0.f;
  for (int k = seg * 512; k < seg * 512 + 512; ++k) {
    float cv = (float)cb[k] * (1.0f / 16777216.0f);
    acc += cv * xb[(size_t)k * D_];
  }
  part[seg][d] = acc;
  __syncthreads();
  if (threadIdx.x < 64) {
    float s = part[0][d] + part[1][d] + part[2][d] + part[3][d];
    csum[b * D_ + h * 64 + d] = s;
  }
}

// out0[b][d] = sum_e csum[b][e] * W[d][e] + S * bias[d]
__global__ __launch_bounds__(256) void proj_k(const float* __restrict__ csum,
                                              const float* __restrict__ W,
                                              const float* __restrict__ bias,
                                              float* __restrict__ out0) {
  const int idx = blockIdx.x * 4 + (threadIdx.x >> 6); // (b,d) pair per wave
  const int b = idx >> 10, d = idx & 1023;
  const int lane = threadIdx.x & 63;
  const float* wr = W + (size_t)d * D_;
  const float* cs = csum + b * D_;
  float acc = 0.f;
#pragma unroll
  for (int e = 0; e < 16; ++e) acc += cs[lane + e * 64] * wr[lane + e * 64];
  acc += __shfl_xor(acc, 32);
  acc += __shfl_xor(acc, 16);
  acc += __shfl_xor(acc, 8);
  acc += __shfl_xor(acc, 4);
  acc += __shfl_xor(acc, 2);
  acc += __shfl_xor(acc, 1);
  if (lane == 0) out0[idx] = acc + 2048.0f * bias[d];
}

extern "C" void kernel_launch(void* const* d_in, const int* in_sizes, int n_in,
                              void* d_out, int out_size, void* d_ws, size_t ws_size,
                              hipStream_t stream) {
  const float* x    = (const float*)d_in[0];
  const int*   sl   = (const int*)d_in[1];
  const float* W    = (const float*)d_in[2];
  const float* bias = (const float*)d_in[3];

  float* out0 = (float*)d_out;
  float* attn = out0 + B_ * D_;

  unsigned long long* c64 = (unsigned long long*)d_ws;   // 64*2048*8 = 1 MB
  float* csum = (float*)(c64 + 64 * 2048);               // 4096 f32

  hipMemsetAsync(c64, 0, (size_t)64 * 2048 * 8, stream);
  hipLaunchKernelGGL(attn_fused, dim3(8192), dim3(256), 0, stream,
                     x, sl, attn, c64);
  hipLaunchKernelGGL(csum_k, dim3(64),   dim3(256), 0, stream, c64, x, csum);
  hipLaunchKernelGGL(proj_k, dim3(1024), dim3(256), 0, stream, csum, W, bias, out0);
}

// Round 3
// 564.159 us; speedup vs baseline: 1.2108x; 1.2108x over previous
//
#include <hip/hip_runtime.h>

// Problem constants
#define S_  2048
#define D_  1024
#define H_  16
#define B_  4

typedef __attribute__((ext_vector_type(8))) short short8;
typedef __attribute__((ext_vector_type(4))) float f32x4;

__device__ __forceinline__ unsigned short f2bf(float f) {
  unsigned int u = __float_as_uint(f);
  u += 0x7fffu + ((u >> 16) & 1u);      // round-to-nearest-even
  return (unsigned short)(u >> 16);
}
__device__ __forceinline__ unsigned int pack2(float a, float b) {
  return (unsigned int)f2bf(a) | ((unsigned int)f2bf(b) << 16);
}

// 0.125 (1/sqrt(DK)) * log2(e): use exp2 (native v_exp_f32)
#define SCL 0.18033688011112042f

// ---------------------------------------------------------------------------
// x (B,S,D) f32 -> xh (B,H,S,64) bf16, head-major so each (b,h) K-slice is
// 256 KB contiguous (L2-resident). grid = 64 bh x 32 chunks, 256 thr.
// ---------------------------------------------------------------------------
__global__ __launch_bounds__(256) void xcvt(const float* __restrict__ x,
                                            unsigned short* __restrict__ xh) {
  const int n = blockIdx.x;
  const int bh = n >> 5, chunk = n & 31;
  const int b = bh >> 4, h = bh & 15;
  const int r = threadIdx.x >> 2, cg = threadIdx.x & 3;
  const int srow = chunk * 64 + r;
  const float* src = x + ((size_t)b * S_ + srow) * D_ + h * 64 + cg * 16;
  float4 v0 = ((const float4*)src)[0];
  float4 v1 = ((const float4*)src)[1];
  float4 v2 = ((const float4*)src)[2];
  float4 v3 = ((const float4*)src)[3];
  uint4 w0, w1;
  w0.x = pack2(v0.x, v0.y); w0.y = pack2(v0.z, v0.w);
  w0.z = pack2(v1.x, v1.y); w0.w = pack2(v1.z, v1.w);
  w1.x = pack2(v2.x, v2.y); w1.y = pack2(v2.z, v2.w);
  w1.z = pack2(v3.x, v3.y); w1.w = pack2(v3.z, v3.w);
  unsigned short* dst = xh + ((size_t)bh * S_ + srow) * 64 + cg * 16;
  *(uint4*)dst = w0;
  *(uint4*)(dst + 8) = w1;
}

// ---------------------------------------------------------------------------
// Fused attention, direct-from-L2 fragments (no LDS staging, no conversion).
// Block = 256 thr (4 waves x 16 q-rows) = 64-row q-tile, full S keys.
// Pass A: QK^T (MFMA) + exp -> row sums. Pass B: recompute, write attn
// (nontemporal) + deterministic per-block column partials (cpart).
// grid = 2048, XCD-swizzled: 8 bh-slices per XCD -> 2 MB L2 working set.
// ---------------------------------------------------------------------------
__global__ __launch_bounds__(256) void attn_fused(
    const unsigned short* __restrict__ xh, const int* __restrict__ sl32,
    float* __restrict__ attn, float* __restrict__ cpart)
{
  __shared__ float colbuf[4][128];

  const int n    = blockIdx.x;
  const int xcd  = n & 7;
  const int slot = n >> 3;                 // 0..255 per XCD
  const int bh   = (slot >> 5) * 8 + xcd;  // 8 bh-slices per XCD
  const int qt   = slot & 31;              // 32 q-tiles of 64 rows
  const int b    = bh >> 4;
  const int tid  = threadIdx.x;
  const int wv   = tid >> 6;
  const int lane = tid & 63;
  const int lo   = lane & 15;
  const int g    = lane >> 4;

  // seq_lens dtype auto-detect (values >= 1024 -> int64 layout has word1==0)
  const bool is64 = (sl32[1] == 0);
  const int seqlen = is64 ? sl32[2 * b] : sl32[b];

  const int qbase = qt * 64 + wv * 16;
  const unsigned short* xk = xh + (size_t)bh * S_ * 64;

  // Q fragment (A-frag): row = lo, k = g*8 + i + 32*s
  short8 aq0 = *(const short8*)(xk + (size_t)(qbase + lo) * 64 + g * 8);
  short8 aq1 = *(const short8*)(xk + (size_t)(qbase + lo) * 64 + g * 8 + 32);

  // B-frag base: key row = kt*16 + lo, k = g*8 + i + 32*s
  const unsigned short* kp = xk + (size_t)lo * 64 + g * 8;

  // ---------------- Pass A: row sums ----------------
  float rsum[4] = {0.f, 0.f, 0.f, 0.f};
#pragma unroll 4
  for (int kt = 0; kt < 128; ++kt) {
    const unsigned short* kpt = kp + (size_t)kt * 1024;
    short8 b0 = *(const short8*)(kpt);
    short8 b1 = *(const short8*)(kpt + 32);
    f32x4 acc = {0.f, 0.f, 0.f, 0.f};
    acc = __builtin_amdgcn_mfma_f32_16x16x32_bf16(aq0, b0, acc, 0, 0, 0);
    acc = __builtin_amdgcn_mfma_f32_16x16x32_bf16(aq1, b1, acc, 0, 0, 0);
    const bool valid = kt * 16 + lo < seqlen;
#pragma unroll
    for (int r = 0; r < 4; ++r)
      rsum[r] += valid ? exp2f(acc[r] * SCL) : 0.f;
  }
#pragma unroll
  for (int r = 0; r < 4; ++r) {
    float v = rsum[r];
    v += __shfl_xor(v, 1);
    v += __shfl_xor(v, 2);
    v += __shfl_xor(v, 4);
    v += __shfl_xor(v, 8);
    rsum[r] = 1.0f / v;                 // 1/l for rows g*4+r
  }

  // ---------------- Pass B: write attn + column partials ----------------
  float* pr = attn + (size_t)bh * S_ * S_ + (size_t)(qbase + g * 4) * S_ + lo;
  float* cp = cpart + ((size_t)bh * 32 + qt) * 2048;
  for (int c0 = 0; c0 < 16; ++c0) {
#pragma unroll
    for (int k8 = 0; k8 < 8; ++k8) {
      const int kt = c0 * 8 + k8;
      const unsigned short* kpt = kp + (size_t)kt * 1024;
      short8 b0 = *(const short8*)(kpt);
      short8 b1 = *(const short8*)(kpt + 32);
      f32x4 acc = {0.f, 0.f, 0.f, 0.f};
      acc = __builtin_amdgcn_mfma_f32_16x16x32_bf16(aq0, b0, acc, 0, 0, 0);
      acc = __builtin_amdgcn_mfma_f32_16x16x32_bf16(aq1, b1, acc, 0, 0, 0);
      const bool valid = kt * 16 + lo < seqlen;
      float a0 = valid ? exp2f(acc[0] * SCL) * rsum[0] : 0.f;
      float a1 = valid ? exp2f(acc[1] * SCL) * rsum[1] : 0.f;
      float a2 = valid ? exp2f(acc[2] * SCL) * rsum[2] : 0.f;
      float a3 = valid ? exp2f(acc[3] * SCL) * rsum[3] : 0.f;
      const int off = kt * 16;
      __builtin_nontemporal_store(a0, pr + off);
      __builtin_nontemporal_store(a1, pr + (size_t)1 * S_ + off);
      __builtin_nontemporal_store(a2, pr + (size_t)2 * S_ + off);
      __builtin_nontemporal_store(a3, pr + (size_t)3 * S_ + off);
      float cv = a0 + a1 + a2 + a3;
      cv += __shfl_xor(cv, 16);
      cv += __shfl_xor(cv, 32);         // 16-row column sum
      if (lane < 16) colbuf[wv][k8 * 16 + lo] = cv;
    }
    __syncthreads();
    if (tid < 128)
      cp[c0 * 128 + tid] = colbuf[0][tid] + colbuf[1][tid] +
                           colbuf[2][tid] + colbuf[3][tid];
    __syncthreads();
  }
}

// c[bh][k] = sum over 32 q-tiles of cpart
__global__ __launch_bounds__(256) void creduce(const float* __restrict__ cpart,
                                               float* __restrict__ c) {
  const int i = blockIdx.x * 256 + threadIdx.x;   // 64*2048 total
  const int bh = i >> 11, k = i & 2047;
  float s = 0.f;
#pragma unroll 8
  for (int qt = 0; qt < 32; ++qt) s += cpart[((size_t)bh * 32 + qt) * 2048 + k];
  c[i] = s;
}

// csum[b][h*64+d] = sum_k c[bh][k] * x[b][k][h*64+d]
__global__ __launch_bounds__(256) void csum_k(const float* __restrict__ c,
                                              const float* __restrict__ x,
                                              float* __restrict__ csum) {
  __shared__ float part[4][64];
  const int bh = blockIdx.x, b = bh >> 4, h = bh & 15;
  const int seg = threadIdx.x >> 6, d = threadIdx.x & 63;
  const float* cb = c + bh * 2048;
  const float* xb = x + (size_t)b * S_ * D_ + h * 64 + d;
  float acc = 0.f;
  for (int k = seg * 512; k < seg * 512 + 512; ++k)
    acc += cb[k] * xb[(size_t)k * D_];
  part[seg][d] = acc;
  __syncthreads();
  if (threadIdx.x < 64) {
    float s = part[0][d] + part[1][d] + part[2][d] + part[3][d];
    csum[b * D_ + h * 64 + d] = s;
  }
}

// out0[b][d] = sum_e csum[b][e] * W[d][e] + S * bias[d]
__global__ __launch_bounds__(256) void proj_k(const float* __restrict__ csum,
                                              const float* __restrict__ W,
                                              const float* __restrict__ bias,
                                              float* __restrict__ out0) {
  const int idx = blockIdx.x * 4 + (threadIdx.x >> 6); // (b,d) pair per wave
  const int b = idx >> 10, d = idx & 1023;
  const int lane = threadIdx.x & 63;
  const float* wr = W + (size_t)d * D_;
  const float* cs = csum + b * D_;
  float acc = 0.f;
#pragma unroll
  for (int e = 0; e < 16; ++e) acc += cs[lane + e * 64] * wr[lane + e * 64];
  acc += __shfl_xor(acc, 32);
  acc += __shfl_xor(acc, 16);
  acc += __shfl_xor(acc, 8);
  acc += __shfl_xor(acc, 4);
  acc += __shfl_xor(acc, 2);
  acc += __shfl_xor(acc, 1);
  if (lane == 0) out0[idx] = acc + 2048.0f * bias[d];
}

extern "C" void kernel_launch(void* const* d_in, const int* in_sizes, int n_in,
                              void* d_out, int out_size, void* d_ws, size_t ws_size,
                              hipStream_t stream) {
  const float* x    = (const float*)d_in[0];
  const int*   sl   = (const int*)d_in[1];
  const float* W    = (const float*)d_in[2];
  const float* bias = (const float*)d_in[3];

  float* out0 = (float*)d_out;
  float* attn = out0 + B_ * D_;

  float* cpart = (float*)d_ws;                       // 64*32*2048 f32 = 16 MB
  float* c     = cpart + (size_t)64 * 32 * 2048;     // 64*2048 f32 = 512 KB
  float* csum  = c + 64 * 2048;                      // 4096 f32 = 16 KB
  unsigned short* xh = (unsigned short*)(csum + 4096); // bf16, 16 MB

  hipLaunchKernelGGL(xcvt,       dim3(2048), dim3(256), 0, stream, x, xh);
  hipLaunchKernelGGL(attn_fused, dim3(2048), dim3(256), 0, stream, xh, sl, attn, cpart);
  hipLaunchKernelGGL(creduce,    dim3(512),  dim3(256), 0, stream, cpart, c);
  hipLaunchKernelGGL(csum_k,     dim3(64),   dim3(256), 0, stream, c, x, csum);
  hipLaunchKernelGGL(proj_k,     dim3(1024), dim3(256), 0, stream, csum, W, bias, out0);
}